// Round 1
// baseline (223.642 us; speedup 1.0000x reference)
//
#include <hip/hip_runtime.h>
#include <math.h>

#define BB 4
#define SS 2048
#define HH 768
#define MAXSEG 256
#define NUM_POS (BB*(SS/4))   // 2048
#define NEG_BIG -1000000000.0f

// ---------------------------------------------------------------------------
// Kernel A: per-batch segment scan + positive-label scan (one block per batch)
// ---------------------------------------------------------------------------
__global__ __launch_bounds__(256) void k_scan(
    const int* __restrict__ ind, const int* __restrict__ clc,
    int* __restrict__ seg_id, int* __restrict__ seg_start,
    int* __restrict__ nseg, int* __restrict__ pos_local, int* __restrict__ pos_cnt)
{
  int b = blockIdx.x, t = threadIdx.x;
  __shared__ int sInd[SS];
  __shared__ int sScan[256];
  for (int i = t; i < SS; i += 256) sInd[i] = ind[b*SS + i];
  __syncthreads();

  // --- segment boundaries: flag[i] = indicator[i] != indicator[i-1] ---
  int i0 = t * 8;
  int f[8]; int lsum = 0;
  for (int u = 0; u < 8; u++) {
    int i = i0 + u;
    f[u] = (i == 0) ? 0 : (sInd[i] != sInd[i-1]);
    lsum += f[u];
  }
  sScan[t] = lsum; __syncthreads();
  for (int off = 1; off < 256; off <<= 1) {
    int v = (t >= off) ? sScan[t-off] : 0;
    __syncthreads();
    sScan[t] += v;
    __syncthreads();
  }
  int run = sScan[t] - lsum;  // exclusive prefix of boundary count
  for (int u = 0; u < 8; u++) {
    int i = i0 + u;
    run += f[u];
    seg_id[b*SS + i] = run;
    if (f[u] || i == 0) seg_start[b*(MAXSEG+1) + run] = i;
  }
  if (t == 255) { nseg[b] = run + 1; seg_start[b*(MAXSEG+1) + run + 1] = SS; }
  __syncthreads();

  // --- positives (clc_label > 0), rank within batch ---
  int p[8]; int psum = 0;
  for (int u = 0; u < 8; u++) {
    int i = i0 + u;
    p[u] = (clc[b*SS + i] > 0) ? 1 : 0;
    psum += p[u];
  }
  sScan[t] = psum; __syncthreads();
  for (int off = 1; off < 256; off <<= 1) {
    int v = (t >= off) ? sScan[t-off] : 0;
    __syncthreads();
    sScan[t] += v;
    __syncthreads();
  }
  int rank = sScan[t] - psum;
  for (int u = 0; u < 8; u++) {
    int i = i0 + u;
    if (p[u]) { pos_local[b*SS + rank] = i; rank++; }
  }
  if (t == 255) pos_cnt[b] = rank;
}

// ---------------------------------------------------------------------------
// Kernel: cross-batch prefix of positive counts (B=4, trivial)
// ---------------------------------------------------------------------------
__global__ void k_base(const int* __restrict__ pos_cnt, int* __restrict__ pos_base)
{
  pos_base[0] = 0;
  for (int b = 0; b < BB; b++) pos_base[b+1] = pos_base[b] + pos_cnt[b];
}

// ---------------------------------------------------------------------------
// Kernel B: segment sums. Block (b,s): 256 threads, 3 H-columns per thread.
// ---------------------------------------------------------------------------
__global__ __launch_bounds__(256) void k_segsum(
    const float* __restrict__ es, const int* __restrict__ seg_start,
    const int* __restrict__ nseg, float* __restrict__ segsum)
{
  int bs = blockIdx.x;
  int b = bs >> 8, s = bs & 255;
  if (s >= nseg[b]) return;
  int st = seg_start[b*(MAXSEG+1) + s];
  int en = seg_start[b*(MAXSEG+1) + s + 1];
  int t = threadIdx.x;
  const float* base = es + (size_t)b*SS*HH;
  float a0 = 0.f, a1 = 0.f, a2 = 0.f;
  for (int i = st; i < en; i++) {
    const float* r = base + (size_t)i*HH;
    a0 += r[t]; a1 += r[t+256]; a2 += r[t+512];
  }
  float* o = segsum + ((size_t)b*MAXSEG + s)*HH;
  o[t] = a0; o[t+256] = a1; o[t+512] = a2;
}

// ---------------------------------------------------------------------------
// Kernel C: U = tanh(segsum @ W^T + bias). R=1024, K=N=768. 32x32 tiles,
// 256 threads (16x16), 2x2 per thread, BK=32, NT layout (both K-contiguous).
// ---------------------------------------------------------------------------
__global__ __launch_bounds__(256) void k_gemmU(
    const float* __restrict__ A, const float* __restrict__ W,
    const float* __restrict__ bias, float* __restrict__ U)
{
  __shared__ float As[32][33];
  __shared__ float Ws[32][33];
  int tx = threadIdx.x & 15, ty = threadIdx.x >> 4;
  int rb = blockIdx.x * 32, ob = blockIdx.y * 32;
  float a00 = 0.f, a01 = 0.f, a10 = 0.f, a11 = 0.f;
  for (int k0 = 0; k0 < HH; k0 += 32) {
    int row = threadIdx.x >> 3, kv = (threadIdx.x & 7) * 4;
    float4 av = *(const float4*)(A + (size_t)(rb + row)*HH + k0 + kv);
    As[row][kv] = av.x; As[row][kv+1] = av.y; As[row][kv+2] = av.z; As[row][kv+3] = av.w;
    float4 wv = *(const float4*)(W + (size_t)(ob + row)*HH + k0 + kv);
    Ws[row][kv] = wv.x; Ws[row][kv+1] = wv.y; Ws[row][kv+2] = wv.z; Ws[row][kv+3] = wv.w;
    __syncthreads();
    #pragma unroll
    for (int kk = 0; kk < 32; kk++) {
      float x0 = As[ty*2][kk], x1 = As[ty*2+1][kk];
      float w0 = Ws[tx*2][kk], w1 = Ws[tx*2+1][kk];
      a00 += x0*w0; a01 += x0*w1; a10 += x1*w0; a11 += x1*w1;
    }
    __syncthreads();
  }
  int r0 = rb + ty*2, o0 = ob + tx*2;
  float b0 = bias[o0], b1 = bias[o0+1];
  U[(size_t)r0*HH + o0]       = tanhf(a00 + b0);
  U[(size_t)r0*HH + o0+1]     = tanhf(a01 + b1);
  U[(size_t)(r0+1)*HH + o0]   = tanhf(a10 + b0);
  U[(size_t)(r0+1)*HH + o0+1] = tanhf(a11 + b1);
}

// ---------------------------------------------------------------------------
// Kernel D: per-batch Gram matrix G[b][s1][s2] = U[b,s1,:].U[b,s2,:]
// ---------------------------------------------------------------------------
__global__ __launch_bounds__(256) void k_gram(
    const float* __restrict__ U, float* __restrict__ G)
{
  int b = blockIdx.z;
  const float* Ub = U + (size_t)b*MAXSEG*HH;
  __shared__ float As[32][33];
  __shared__ float Bs[32][33];
  int tx = threadIdx.x & 15, ty = threadIdx.x >> 4;
  int rb = blockIdx.x * 32, cb = blockIdx.y * 32;
  float a00 = 0.f, a01 = 0.f, a10 = 0.f, a11 = 0.f;
  for (int k0 = 0; k0 < HH; k0 += 32) {
    int row = threadIdx.x >> 3, kv = (threadIdx.x & 7) * 4;
    float4 av = *(const float4*)(Ub + (size_t)(rb + row)*HH + k0 + kv);
    As[row][kv] = av.x; As[row][kv+1] = av.y; As[row][kv+2] = av.z; As[row][kv+3] = av.w;
    float4 bv = *(const float4*)(Ub + (size_t)(cb + row)*HH + k0 + kv);
    Bs[row][kv] = bv.x; Bs[row][kv+1] = bv.y; Bs[row][kv+2] = bv.z; Bs[row][kv+3] = bv.w;
    __syncthreads();
    #pragma unroll
    for (int kk = 0; kk < 32; kk++) {
      float x0 = As[ty*2][kk], x1 = As[ty*2+1][kk];
      float y0 = Bs[tx*2][kk], y1 = Bs[tx*2+1][kk];
      a00 += x0*y0; a01 += x0*y1; a10 += x1*y0; a11 += x1*y1;
    }
    __syncthreads();
  }
  int s1 = rb + ty*2, s2 = cb + tx*2;
  float* Gb = G + (size_t)b*MAXSEG*MAXSEG;
  Gb[(size_t)s1*MAXSEG + s2]       = a00;
  Gb[(size_t)s1*MAXSEG + s2+1]     = a01;
  Gb[(size_t)(s1+1)*MAXSEG + s2]   = a10;
  Gb[(size_t)(s1+1)*MAXSEG + s2+1] = a11;
}

// ---------------------------------------------------------------------------
// Kernel E: per positive row — masked softmax CE + first-occurrence argmax.
// One block (256 threads) per positive row r (global order = flat index order).
// ---------------------------------------------------------------------------
__global__ __launch_bounds__(256) void k_rows(
    const float* __restrict__ G, const int* __restrict__ seg_id,
    const int* __restrict__ clc, const int* __restrict__ pos_local,
    const int* __restrict__ pos_base, float* __restrict__ accum)
{
  int r = blockIdx.x;
  int b = 0;
  while (b < BB-1 && r >= pos_base[b+1]) b++;
  if (r >= pos_base[b+1]) return;
  int k = r - pos_base[b];
  int i = pos_local[b*SS + k];
  int si = seg_id[b*SS + i];
  int L  = clc[b*SS + i];

  __shared__ float Grow[MAXSEG];
  __shared__ float sVal[256];
  __shared__ int   sIdx[256];
  int t = threadIdx.x;
  Grow[t] = G[((size_t)b*MAXSEG + si)*MAXSEG + t];
  __syncthreads();

  const int* sid = seg_id + b*SS;
  const int* cl  = clc + b*SS;

  // pass 1: max + first-index argmax
  float mv = -INFINITY; int mi = SS;
  for (int j = t; j < SS; j += 256) {
    float v = Grow[sid[j]] + (cl[j] < 0 ? 0.0f : NEG_BIG);
    if (v > mv) { mv = v; mi = j; }
  }
  sVal[t] = mv; sIdx[t] = mi; __syncthreads();
  for (int off = 128; off > 0; off >>= 1) {
    if (t < off) {
      float v2 = sVal[t+off]; int i2 = sIdx[t+off];
      if (v2 > sVal[t] || (v2 == sVal[t] && i2 < sIdx[t])) { sVal[t] = v2; sIdx[t] = i2; }
    }
    __syncthreads();
  }
  float gmax = sVal[0]; int gidx = sIdx[0];
  __syncthreads();

  // pass 2: sum of exp(v - gmax); masked columns underflow to exactly 0
  float se = 0.f;
  for (int j = t; j < SS; j += 256) {
    float v = Grow[sid[j]] + (cl[j] < 0 ? 0.0f : NEG_BIG);
    se += expf(v - gmax);
  }
  sVal[t] = se; __syncthreads();
  for (int off = 128; off > 0; off >>= 1) {
    if (t < off) sVal[t] += sVal[t+off];
    __syncthreads();
  }
  if (t == 0) {
    float vL = Grow[sid[L]] + (cl[L] < 0 ? 0.0f : NEG_BIG);
    float loss = -(vL - gmax - logf(sVal[0]));
    int p = r & 1;  // 0 = sep (even global rank), 1 = tok
    atomicAdd(&accum[p*2],     loss);
    atomicAdd(&accum[p*2 + 1], (gidx == L) ? 1.0f : 0.0f);
  }
}

// ---------------------------------------------------------------------------
// Kernel F: finalize the 6 scalars
// ---------------------------------------------------------------------------
__global__ void k_final(const float* __restrict__ accum, float* __restrict__ out)
{
  float n = (float)(NUM_POS/2);        // 1024
  out[0] = accum[0] / n;               // sep_loss
  out[1] = accum[1];                   // sep_correct
  out[2] = n + 1e-6f;                  // sep_count (rounds to 1024.0f, matches f32 cast)
  out[3] = accum[2] / n;               // tok_loss
  out[4] = accum[3];                   // tok_correct
  out[5] = n + 1e-6f;                  // tok_count
}

// ---------------------------------------------------------------------------
extern "C" void kernel_launch(void* const* d_in, const int* in_sizes, int n_in,
                              void* d_out, int out_size, void* d_ws, size_t ws_size,
                              hipStream_t stream)
{
  const float* es   = (const float*)d_in[0];   // (B,S,H)
  const float* W    = (const float*)d_in[1];   // (H,H)
  const float* bias = (const float*)d_in[2];   // (H,)
  const int*   ind  = (const int*)d_in[3];     // (B,S)
  const int*   clc  = (const int*)d_in[4];     // (B,S)
  float* out = (float*)d_out;

  char* ws = (char*)d_ws;
  float* accum     = (float*)(ws + 0);                 // 4 floats
  int*   nseg      = (int*)(ws + 256);                 // B
  int*   pos_cnt   = (int*)(ws + 512);                 // B
  int*   pos_base  = (int*)(ws + 768);                 // B+1
  int*   seg_start = (int*)(ws + 1024);                // B*(MAXSEG+1)
  int*   seg_id    = (int*)(ws + 8192);                // B*S
  int*   pos_local = (int*)(ws + 8192 + 32768);        // B*S
  float* segsum    = (float*)(ws + 73728);             // B*256*768
  float* U         = (float*)(ws + 73728 + 3145728);   // B*256*768
  float* G         = (float*)(ws + 73728 + 2*3145728); // B*256*256

  hipMemsetAsync(accum, 0, 16, stream);

  k_scan<<<BB, 256, 0, stream>>>(ind, clc, seg_id, seg_start, nseg, pos_local, pos_cnt);
  k_base<<<1, 1, 0, stream>>>(pos_cnt, pos_base);
  k_segsum<<<BB*MAXSEG, 256, 0, stream>>>(es, seg_start, nseg, segsum);
  dim3 gC(1024/32, HH/32);
  k_gemmU<<<gC, 256, 0, stream>>>(segsum, W, bias, U);
  dim3 gD(MAXSEG/32, MAXSEG/32, BB);
  k_gram<<<gD, 256, 0, stream>>>(U, G);
  k_rows<<<NUM_POS, 256, 0, stream>>>(G, seg_id, clc, pos_local, pos_base, accum);
  k_final<<<1, 1, 0, stream>>>(accum, out);
}

// Round 2
// 183.825 us; speedup vs baseline: 1.2166x; 1.2166x over previous
//
#include <hip/hip_runtime.h>
#include <math.h>
#include <limits.h>

#define BB 4
#define SS 2048
#define HH 768
#define MAXSEG 256
#define NUM_POS (BB*(SS/4))   // 2048
#define NEG_BIG -1000000000.0f

// ---------------------------------------------------------------------------
// Kernel A: per-batch scans (one block per batch, shfl-based)
//  - segment ids + segment starts + nseg
//  - per-segment allowed-column count + first allowed column index
//  - positive (clc>0) ranks
// ---------------------------------------------------------------------------
__global__ __launch_bounds__(256) void k_scan(
    const int* __restrict__ ind, const int* __restrict__ clc,
    int* __restrict__ seg_id, int* __restrict__ seg_start,
    int* __restrict__ nseg, int* __restrict__ pos_local, int* __restrict__ pos_cnt,
    int* __restrict__ allowCnt, int* __restrict__ firstAllow)
{
  int b = blockIdx.x, t = threadIdx.x;
  int lane = t & 63, wid = t >> 6;
  __shared__ int sInd[SS];
  __shared__ int sWave[4];
  __shared__ int sAC[MAXSEG];
  __shared__ int sFA[MAXSEG];
  for (int i = t; i < SS; i += 256) sInd[i] = ind[b*SS + i];
  sAC[t] = 0; sFA[t] = INT_MAX;
  __syncthreads();

  int i0 = t * 8;
  int f[8], cv[8];
  int lsum = 0;
  #pragma unroll
  for (int u = 0; u < 8; u++) {
    int i = i0 + u;
    f[u] = (i == 0) ? 0 : (sInd[i] != sInd[i-1]);
    cv[u] = clc[b*SS + i];
    lsum += f[u];
  }
  // wave inclusive scan of boundary counts
  int x = lsum;
  #pragma unroll
  for (int off = 1; off < 64; off <<= 1) {
    int v = __shfl_up(x, off, 64);
    if (lane >= off) x += v;
  }
  if (lane == 63) sWave[wid] = x;
  __syncthreads();
  int base = 0;
  for (int w = 0; w < wid; w++) base += sWave[w];
  int run = base + x - lsum;  // exclusive prefix
  int rid[8];
  #pragma unroll
  for (int u = 0; u < 8; u++) {
    int i = i0 + u;
    run += f[u];
    rid[u] = run;
    seg_id[b*SS + i] = run;
    if (f[u] || i == 0) seg_start[b*(MAXSEG+1) + run] = i;
  }
  if (t == 255) { nseg[b] = run + 1; seg_start[b*(MAXSEG+1) + run + 1] = SS; }

  // allowed-column stats per segment
  #pragma unroll
  for (int u = 0; u < 8; u++) {
    if (cv[u] < 0) {
      atomicAdd(&sAC[rid[u]], 1);
      atomicMin(&sFA[rid[u]], i0 + u);
    }
  }
  __syncthreads();
  allowCnt[b*MAXSEG + t]   = sAC[t];
  firstAllow[b*MAXSEG + t] = sFA[t];

  // positive ranks
  int psum = 0;
  int p[8];
  #pragma unroll
  for (int u = 0; u < 8; u++) { p[u] = (cv[u] > 0) ? 1 : 0; psum += p[u]; }
  x = psum;
  #pragma unroll
  for (int off = 1; off < 64; off <<= 1) {
    int v = __shfl_up(x, off, 64);
    if (lane >= off) x += v;
  }
  __syncthreads();           // sWave reuse
  if (lane == 63) sWave[wid] = x;
  __syncthreads();
  base = 0;
  for (int w = 0; w < wid; w++) base += sWave[w];
  int rank = base + x - psum;
  #pragma unroll
  for (int u = 0; u < 8; u++) {
    if (p[u]) { pos_local[b*SS + rank] = i0 + u; rank++; }
  }
  if (t == 255) pos_cnt[b] = rank;
}

// ---------------------------------------------------------------------------
// Kernel B: segment sums. Block (b,s): 256 threads, 3 H-columns per thread.
// ---------------------------------------------------------------------------
__global__ __launch_bounds__(256) void k_segsum(
    const float* __restrict__ es, const int* __restrict__ seg_start,
    const int* __restrict__ nseg, float* __restrict__ segsum)
{
  int bs = blockIdx.x;
  int b = bs >> 8, s = bs & 255;
  if (s >= nseg[b]) return;
  int st = seg_start[b*(MAXSEG+1) + s];
  int en = seg_start[b*(MAXSEG+1) + s + 1];
  int t = threadIdx.x;
  const float* base = es + (size_t)b*SS*HH;
  float a0 = 0.f, a1 = 0.f, a2 = 0.f;
  for (int i = st; i < en; i++) {
    const float* r = base + (size_t)i*HH;
    a0 += r[t]; a1 += r[t+256]; a2 += r[t+512];
  }
  float* o = segsum + ((size_t)b*MAXSEG + s)*HH;
  o[t] = a0; o[t+256] = a1; o[t+512] = a2;
}

// ---------------------------------------------------------------------------
// Kernel C: U = tanh(segsum @ W^T + bias). 64x64 tile, 4x4/thread, BK=16,
// LDS stored K-major (transposed) so fragment reads are ds_read_b128.
// ---------------------------------------------------------------------------
__global__ __launch_bounds__(256) void k_gemmU(
    const float* __restrict__ A, const float* __restrict__ W,
    const float* __restrict__ bias, float* __restrict__ U)
{
  __shared__ __align__(16) float As[16][68];
  __shared__ __align__(16) float Ws[16][68];
  int tid = threadIdx.x;
  int tx = tid & 15, ty = tid >> 4;
  int rb = blockIdx.x * 64, ob = blockIdx.y * 64;
  int lrow = tid >> 2;         // 0..63
  int lk   = (tid & 3) * 4;    // 0,4,8,12
  float acc[4][4] = {};
  for (int k0 = 0; k0 < HH; k0 += 16) {
    float4 av = *(const float4*)(A + (size_t)(rb + lrow)*HH + k0 + lk);
    float4 wv = *(const float4*)(W + (size_t)(ob + lrow)*HH + k0 + lk);
    __syncthreads();
    As[lk+0][lrow] = av.x; As[lk+1][lrow] = av.y; As[lk+2][lrow] = av.z; As[lk+3][lrow] = av.w;
    Ws[lk+0][lrow] = wv.x; Ws[lk+1][lrow] = wv.y; Ws[lk+2][lrow] = wv.z; Ws[lk+3][lrow] = wv.w;
    __syncthreads();
    #pragma unroll
    for (int kk = 0; kk < 16; kk++) {
      float4 a4 = *(const float4*)&As[kk][ty*4];
      float4 b4 = *(const float4*)&Ws[kk][tx*4];
      acc[0][0] += a4.x*b4.x; acc[0][1] += a4.x*b4.y; acc[0][2] += a4.x*b4.z; acc[0][3] += a4.x*b4.w;
      acc[1][0] += a4.y*b4.x; acc[1][1] += a4.y*b4.y; acc[1][2] += a4.y*b4.z; acc[1][3] += a4.y*b4.w;
      acc[2][0] += a4.z*b4.x; acc[2][1] += a4.z*b4.y; acc[2][2] += a4.z*b4.z; acc[2][3] += a4.z*b4.w;
      acc[3][0] += a4.w*b4.x; acc[3][1] += a4.w*b4.y; acc[3][2] += a4.w*b4.z; acc[3][3] += a4.w*b4.w;
    }
  }
  int col = ob + tx*4;
  float4 bv = *(const float4*)(bias + col);
  #pragma unroll
  for (int i = 0; i < 4; i++) {
    int row = rb + ty*4 + i;
    float4 o;
    o.x = tanhf(acc[i][0] + bv.x);
    o.y = tanhf(acc[i][1] + bv.y);
    o.z = tanhf(acc[i][2] + bv.z);
    o.w = tanhf(acc[i][3] + bv.w);
    *(float4*)(U + (size_t)row*HH + col) = o;
  }
}

// ---------------------------------------------------------------------------
// Kernel D: per-batch Gram matrix, same 64x64 / 4x4 structure
// ---------------------------------------------------------------------------
__global__ __launch_bounds__(256) void k_gram(
    const float* __restrict__ U, float* __restrict__ G)
{
  int b = blockIdx.z;
  const float* Ub = U + (size_t)b*MAXSEG*HH;
  __shared__ __align__(16) float As[16][68];
  __shared__ __align__(16) float Bs[16][68];
  int tid = threadIdx.x;
  int tx = tid & 15, ty = tid >> 4;
  int rb = blockIdx.x * 64, cb = blockIdx.y * 64;
  int lrow = tid >> 2;
  int lk   = (tid & 3) * 4;
  float acc[4][4] = {};
  for (int k0 = 0; k0 < HH; k0 += 16) {
    float4 av = *(const float4*)(Ub + (size_t)(rb + lrow)*HH + k0 + lk);
    float4 bvv = *(const float4*)(Ub + (size_t)(cb + lrow)*HH + k0 + lk);
    __syncthreads();
    As[lk+0][lrow] = av.x; As[lk+1][lrow] = av.y; As[lk+2][lrow] = av.z; As[lk+3][lrow] = av.w;
    Bs[lk+0][lrow] = bvv.x; Bs[lk+1][lrow] = bvv.y; Bs[lk+2][lrow] = bvv.z; Bs[lk+3][lrow] = bvv.w;
    __syncthreads();
    #pragma unroll
    for (int kk = 0; kk < 16; kk++) {
      float4 a4 = *(const float4*)&As[kk][ty*4];
      float4 b4 = *(const float4*)&Bs[kk][tx*4];
      acc[0][0] += a4.x*b4.x; acc[0][1] += a4.x*b4.y; acc[0][2] += a4.x*b4.z; acc[0][3] += a4.x*b4.w;
      acc[1][0] += a4.y*b4.x; acc[1][1] += a4.y*b4.y; acc[1][2] += a4.y*b4.z; acc[1][3] += a4.y*b4.w;
      acc[2][0] += a4.z*b4.x; acc[2][1] += a4.z*b4.y; acc[2][2] += a4.z*b4.z; acc[2][3] += a4.z*b4.w;
      acc[3][0] += a4.w*b4.x; acc[3][1] += a4.w*b4.y; acc[3][2] += a4.w*b4.z; acc[3][3] += a4.w*b4.w;
    }
  }
  float* Gb = G + (size_t)b*MAXSEG*MAXSEG;
  int col = cb + tx*4;
  #pragma unroll
  for (int i = 0; i < 4; i++) {
    int row = rb + ty*4 + i;
    float4 o; o.x = acc[i][0]; o.y = acc[i][1]; o.z = acc[i][2]; o.w = acc[i][3];
    *(float4*)(Gb + (size_t)row*MAXSEG + col) = o;
  }
}

// ---------------------------------------------------------------------------
// Kernel E1: per (b,seg) row: segment-level logsumexp + first-occurrence argmax.
// One wave per row (4 waves/block). Also computes pos_base in block 0.
// ---------------------------------------------------------------------------
__global__ __launch_bounds__(256) void k_seglse(
    const float* __restrict__ G, const int* __restrict__ allowCnt,
    const int* __restrict__ firstAllow, const int* __restrict__ nseg,
    const int* __restrict__ pos_cnt, int* __restrict__ pos_base,
    float* __restrict__ lse, int* __restrict__ amax)
{
  if (blockIdx.x == 0 && threadIdx.x == 0) {
    int acc = 0;
    pos_base[0] = 0;
    for (int b = 0; b < BB; b++) { acc += pos_cnt[b]; pos_base[b+1] = acc; }
  }
  int lane = threadIdx.x & 63, wid = threadIdx.x >> 6;
  int row = blockIdx.x * 4 + wid;
  int b = row >> 8, si = row & 255;
  if (si >= nseg[b]) return;
  const float* g = G + ((size_t)b*MAXSEG + si)*MAXSEG;
  const int* ac = allowCnt + b*MAXSEG;
  const int* fa = firstAllow + b*MAXSEG;

  float gv[4]; int av[4], fv[4];
  #pragma unroll
  for (int q = 0; q < 4; q++) {
    int s = lane + 64*q;
    gv[q] = g[s]; av[q] = ac[s]; fv[q] = fa[s];
  }
  // max over allowed segments
  float m = -INFINITY;
  #pragma unroll
  for (int q = 0; q < 4; q++) if (av[q] > 0) m = fmaxf(m, gv[q]);
  #pragma unroll
  for (int off = 32; off > 0; off >>= 1) m = fmaxf(m, __shfl_xor(m, off, 64));
  // weighted exp sum (masked columns underflow to exactly 0, as in reference)
  float s = 0.f;
  #pragma unroll
  for (int q = 0; q < 4; q++) if (av[q] > 0) s += (float)av[q] * expf(gv[q] - m);
  #pragma unroll
  for (int off = 32; off > 0; off >>= 1) s += __shfl_xor(s, off, 64);
  // argmax: best value, tie -> smallest first-allowed column index
  float bv = -INFINITY; int bi = INT_MAX;
  #pragma unroll
  for (int q = 0; q < 4; q++) {
    if (av[q] > 0 && (gv[q] > bv || (gv[q] == bv && fv[q] < bi))) { bv = gv[q]; bi = fv[q]; }
  }
  #pragma unroll
  for (int off = 32; off > 0; off >>= 1) {
    float ov = __shfl_xor(bv, off, 64);
    int   oi = __shfl_xor(bi, off, 64);
    if (ov > bv || (ov == bv && oi < bi)) { bv = ov; bi = oi; }
  }
  if (lane == 0) {
    lse[row]  = m + logf(s);
    amax[row] = bi;
  }
}

// ---------------------------------------------------------------------------
// Kernel E2: per positive row — loss + correct via precomputed lse/amax
// ---------------------------------------------------------------------------
__global__ __launch_bounds__(256) void k_pos(
    const float* __restrict__ G, const int* __restrict__ seg_id,
    const int* __restrict__ clc, const int* __restrict__ pos_local,
    const int* __restrict__ pos_base, const float* __restrict__ lse,
    const int* __restrict__ amax, float* __restrict__ accum)
{
  int r = blockIdx.x*256 + threadIdx.x;
  int lane = threadIdx.x & 63;
  int total = pos_base[BB];
  if (total > NUM_POS) total = NUM_POS;
  float l0 = 0.f, c0 = 0.f, l1 = 0.f, c1 = 0.f;
  if (r < total) {
    int b = 0;
    while (b < BB-1 && r >= pos_base[b+1]) b++;
    int k = r - pos_base[b];
    int i = pos_local[b*SS + k];
    int si = seg_id[b*SS + i];
    int L  = clc[b*SS + i];
    int sL = seg_id[b*SS + L];
    float vL = G[((size_t)b*MAXSEG + si)*MAXSEG + sL] + (clc[b*SS + L] < 0 ? 0.0f : NEG_BIG);
    float loss = lse[b*MAXSEG + si] - vL;
    float corr = (amax[b*MAXSEG + si] == L) ? 1.0f : 0.0f;
    if (r & 1) { l1 = loss; c1 = corr; } else { l0 = loss; c0 = corr; }
  }
  #pragma unroll
  for (int off = 32; off > 0; off >>= 1) {
    l0 += __shfl_down(l0, off, 64);
    c0 += __shfl_down(c0, off, 64);
    l1 += __shfl_down(l1, off, 64);
    c1 += __shfl_down(c1, off, 64);
  }
  if (lane == 0) {
    atomicAdd(&accum[0], l0);
    atomicAdd(&accum[1], c0);
    atomicAdd(&accum[2], l1);
    atomicAdd(&accum[3], c1);
  }
}

// ---------------------------------------------------------------------------
// Kernel F: finalize the 6 scalars
// ---------------------------------------------------------------------------
__global__ void k_final(const float* __restrict__ accum, float* __restrict__ out)
{
  float n = (float)(NUM_POS/2);        // 1024
  out[0] = accum[0] / n;               // sep_loss
  out[1] = accum[1];                   // sep_correct
  out[2] = n + 1e-6f;                  // sep_count
  out[3] = accum[2] / n;               // tok_loss
  out[4] = accum[3];                   // tok_correct
  out[5] = n + 1e-6f;                  // tok_count
}

// ---------------------------------------------------------------------------
extern "C" void kernel_launch(void* const* d_in, const int* in_sizes, int n_in,
                              void* d_out, int out_size, void* d_ws, size_t ws_size,
                              hipStream_t stream)
{
  const float* es   = (const float*)d_in[0];   // (B,S,H)
  const float* W    = (const float*)d_in[1];   // (H,H)
  const float* bias = (const float*)d_in[2];   // (H,)
  const int*   ind  = (const int*)d_in[3];     // (B,S)
  const int*   clc  = (const int*)d_in[4];     // (B,S)
  float* out = (float*)d_out;

  char* ws = (char*)d_ws;
  float* accum      = (float*)(ws + 0);                  // 4 floats
  int*   nseg       = (int*)(ws + 256);                  // B
  int*   pos_cnt    = (int*)(ws + 512);                  // B
  int*   pos_base   = (int*)(ws + 768);                  // B+1
  int*   seg_start  = (int*)(ws + 1024);                 // B*(MAXSEG+1)
  int*   seg_id     = (int*)(ws + 8192);                 // B*S
  int*   pos_local  = (int*)(ws + 40960);                // B*S
  int*   allowCnt   = (int*)(ws + 73728);                // B*256
  int*   firstAllow = (int*)(ws + 77824);                // B*256
  float* lse        = (float*)(ws + 81920);              // B*256
  int*   amax       = (int*)(ws + 86016);                // B*256
  float* segsum     = (float*)(ws + 90112);              // B*256*768
  float* U          = (float*)(ws + 90112 + 3145728);    // B*256*768
  float* G          = (float*)(ws + 90112 + 2*3145728);  // B*256*256

  hipMemsetAsync(accum, 0, 16, stream);

  k_scan<<<BB, 256, 0, stream>>>(ind, clc, seg_id, seg_start, nseg, pos_local,
                                 pos_cnt, allowCnt, firstAllow);
  k_segsum<<<BB*MAXSEG, 256, 0, stream>>>(es, seg_start, nseg, segsum);
  dim3 gC(1024/64, HH/64);
  k_gemmU<<<gC, 256, 0, stream>>>(segsum, W, bias, U);
  dim3 gD(MAXSEG/64, MAXSEG/64, BB);
  k_gram<<<gD, 256, 0, stream>>>(U, G);
  k_seglse<<<(BB*MAXSEG)/4, 256, 0, stream>>>(G, allowCnt, firstAllow, nseg,
                                              pos_cnt, pos_base, lse, amax);
  k_pos<<<(NUM_POS+255)/256, 256, 0, stream>>>(G, seg_id, clc, pos_local,
                                               pos_base, lse, amax, accum);
  k_final<<<1, 1, 0, stream>>>(accum, out);
}

// Round 3
// 172.486 us; speedup vs baseline: 1.2966x; 1.0657x over previous
//
#include <hip/hip_runtime.h>
#include <math.h>
#include <limits.h>

#define BB 4
#define SS 2048
#define HH 768
#define MAXSEG 256
#define NUM_POS (BB*(SS/4))   // 2048
#define NEG_BIG -1000000000.0f

// ---------------------------------------------------------------------------
// Kernel A: per-batch scans (one block per batch, shfl-based)
// ---------------------------------------------------------------------------
__global__ __launch_bounds__(256) void k_scan(
    const int* __restrict__ ind, const int* __restrict__ clc,
    int* __restrict__ seg_id, int* __restrict__ seg_start,
    int* __restrict__ nseg, int* __restrict__ pos_local, int* __restrict__ pos_cnt,
    int* __restrict__ allowCnt, int* __restrict__ firstAllow)
{
  int b = blockIdx.x, t = threadIdx.x;
  int lane = t & 63, wid = t >> 6;
  __shared__ int sInd[SS];
  __shared__ int sWave[4];
  __shared__ int sAC[MAXSEG];
  __shared__ int sFA[MAXSEG];
  for (int i = t; i < SS; i += 256) sInd[i] = ind[b*SS + i];
  sAC[t] = 0; sFA[t] = INT_MAX;
  __syncthreads();

  int i0 = t * 8;
  int f[8], cv[8];
  int lsum = 0;
  #pragma unroll
  for (int u = 0; u < 8; u++) {
    int i = i0 + u;
    f[u] = (i == 0) ? 0 : (sInd[i] != sInd[i-1]);
    cv[u] = clc[b*SS + i];
    lsum += f[u];
  }
  int x = lsum;
  #pragma unroll
  for (int off = 1; off < 64; off <<= 1) {
    int v = __shfl_up(x, off, 64);
    if (lane >= off) x += v;
  }
  if (lane == 63) sWave[wid] = x;
  __syncthreads();
  int base = 0;
  for (int w = 0; w < wid; w++) base += sWave[w];
  int run = base + x - lsum;
  int rid[8];
  #pragma unroll
  for (int u = 0; u < 8; u++) {
    int i = i0 + u;
    run += f[u];
    rid[u] = run;
    seg_id[b*SS + i] = run;
    if (f[u] || i == 0) seg_start[b*(MAXSEG+1) + run] = i;
  }
  if (t == 255) { nseg[b] = run + 1; seg_start[b*(MAXSEG+1) + run + 1] = SS; }

  #pragma unroll
  for (int u = 0; u < 8; u++) {
    if (cv[u] < 0) {
      atomicAdd(&sAC[rid[u]], 1);
      atomicMin(&sFA[rid[u]], i0 + u);
    }
  }
  __syncthreads();
  allowCnt[b*MAXSEG + t]   = sAC[t];
  firstAllow[b*MAXSEG + t] = sFA[t];

  int psum = 0;
  int p[8];
  #pragma unroll
  for (int u = 0; u < 8; u++) { p[u] = (cv[u] > 0) ? 1 : 0; psum += p[u]; }
  x = psum;
  #pragma unroll
  for (int off = 1; off < 64; off <<= 1) {
    int v = __shfl_up(x, off, 64);
    if (lane >= off) x += v;
  }
  __syncthreads();
  if (lane == 63) sWave[wid] = x;
  __syncthreads();
  base = 0;
  for (int w = 0; w < wid; w++) base += sWave[w];
  int rank = base + x - psum;
  #pragma unroll
  for (int u = 0; u < 8; u++) {
    if (p[u]) { pos_local[b*SS + rank] = i0 + u; rank++; }
  }
  if (t == 255) pos_cnt[b] = rank;
}

// ---------------------------------------------------------------------------
// Kernel B: segment sums. Block (b,s): 256 threads, 3 H-columns per thread.
// ---------------------------------------------------------------------------
__global__ __launch_bounds__(256) void k_segsum(
    const float* __restrict__ es, const int* __restrict__ seg_start,
    const int* __restrict__ nseg, float* __restrict__ segsum)
{
  int bs = blockIdx.x;
  int b = bs >> 8, s = bs & 255;
  if (s >= nseg[b]) return;
  int st = seg_start[b*(MAXSEG+1) + s];
  int en = seg_start[b*(MAXSEG+1) + s + 1];
  int t = threadIdx.x;
  const float* base = es + (size_t)b*SS*HH;
  float a0 = 0.f, a1 = 0.f, a2 = 0.f;
  for (int i = st; i < en; i++) {
    const float* r = base + (size_t)i*HH;
    a0 += r[t]; a1 += r[t+256]; a2 += r[t+512];
  }
  float* o = segsum + ((size_t)b*MAXSEG + s)*HH;
  o[t] = a0; o[t+256] = a1; o[t+512] = a2;
}

// ---------------------------------------------------------------------------
// Kernel C: split-K GEMM partial: Uacc += A[rb:rb+64, kz*256:+256] @ W^T.
// 64x64 tile, 4x4/thread, BK=16, K-major LDS, software-pipelined global load.
// grid (16, 12, 3). Uacc must be zeroed.
// ---------------------------------------------------------------------------
__global__ __launch_bounds__(256) void k_gemmU(
    const float* __restrict__ A, const float* __restrict__ W,
    float* __restrict__ Uacc)
{
  __shared__ __align__(16) float As[16][68];
  __shared__ __align__(16) float Ws[16][68];
  int tid = threadIdx.x;
  int tx = tid & 15, ty = tid >> 4;
  int rb = blockIdx.x * 64, ob = blockIdx.y * 64;
  int kbase = blockIdx.z * 256;
  int lrow = tid >> 2;         // 0..63
  int lk   = (tid & 3) * 4;    // 0,4,8,12
  const float* Ap = A + (size_t)(rb + lrow)*HH + kbase + lk;
  const float* Wp = W + (size_t)(ob + lrow)*HH + kbase + lk;
  float4 av = *(const float4*)Ap;
  float4 wv = *(const float4*)Wp;
  float acc[4][4] = {};
  for (int it = 0; it < 16; it++) {
    __syncthreads();
    As[lk+0][lrow] = av.x; As[lk+1][lrow] = av.y; As[lk+2][lrow] = av.z; As[lk+3][lrow] = av.w;
    Ws[lk+0][lrow] = wv.x; Ws[lk+1][lrow] = wv.y; Ws[lk+2][lrow] = wv.z; Ws[lk+3][lrow] = wv.w;
    __syncthreads();
    if (it < 15) {                       // prefetch next tile, overlaps compute
      av = *(const float4*)(Ap + (it+1)*16);
      wv = *(const float4*)(Wp + (it+1)*16);
    }
    #pragma unroll
    for (int kk = 0; kk < 16; kk++) {
      float4 a4 = *(const float4*)&As[kk][ty*4];
      float4 b4 = *(const float4*)&Ws[kk][tx*4];
      acc[0][0] += a4.x*b4.x; acc[0][1] += a4.x*b4.y; acc[0][2] += a4.x*b4.z; acc[0][3] += a4.x*b4.w;
      acc[1][0] += a4.y*b4.x; acc[1][1] += a4.y*b4.y; acc[1][2] += a4.y*b4.z; acc[1][3] += a4.y*b4.w;
      acc[2][0] += a4.z*b4.x; acc[2][1] += a4.z*b4.y; acc[2][2] += a4.z*b4.z; acc[2][3] += a4.z*b4.w;
      acc[3][0] += a4.w*b4.x; acc[3][1] += a4.w*b4.y; acc[3][2] += a4.w*b4.z; acc[3][3] += a4.w*b4.w;
    }
  }
  int col = ob + tx*4;
  #pragma unroll
  for (int i = 0; i < 4; i++) {
    float* dst = Uacc + (size_t)(rb + ty*4 + i)*HH + col;
    atomicAdd(dst+0, acc[i][0]);
    atomicAdd(dst+1, acc[i][1]);
    atomicAdd(dst+2, acc[i][2]);
    atomicAdd(dst+3, acc[i][3]);
  }
}

// ---------------------------------------------------------------------------
// Kernel C2: in-place epilogue U = tanh(Uacc + bias). grid 768 x 256, float4.
// ---------------------------------------------------------------------------
__global__ __launch_bounds__(256) void k_epiU(
    float* __restrict__ Uacc, const float* __restrict__ bias)
{
  int idx = blockIdx.x*256 + threadIdx.x;   // float4 index, 196608 total
  int col4 = idx % (HH/4);
  float4 v = ((float4*)Uacc)[idx];
  float4 bv = ((const float4*)bias)[col4];
  v.x = tanhf(v.x + bv.x);
  v.y = tanhf(v.y + bv.y);
  v.z = tanhf(v.z + bv.z);
  v.w = tanhf(v.w + bv.w);
  ((float4*)Uacc)[idx] = v;
}

// ---------------------------------------------------------------------------
// Kernel D: split-K Gram partial. grid (4, 4, 16): z = b*4 + kz, K=192 each.
// G must be zeroed.
// ---------------------------------------------------------------------------
__global__ __launch_bounds__(256) void k_gram(
    const float* __restrict__ U, float* __restrict__ G)
{
  int b  = blockIdx.z >> 2;
  int kz = blockIdx.z & 3;
  const float* Ub = U + (size_t)b*MAXSEG*HH;
  __shared__ __align__(16) float As[16][68];
  __shared__ __align__(16) float Bs[16][68];
  int tid = threadIdx.x;
  int tx = tid & 15, ty = tid >> 4;
  int rb = blockIdx.x * 64, cb = blockIdx.y * 64;
  int kbase = kz * 192;
  int lrow = tid >> 2;
  int lk   = (tid & 3) * 4;
  const float* Apr = Ub + (size_t)(rb + lrow)*HH + kbase + lk;
  const float* Bpr = Ub + (size_t)(cb + lrow)*HH + kbase + lk;
  float4 av = *(const float4*)Apr;
  float4 bv = *(const float4*)Bpr;
  float acc[4][4] = {};
  for (int it = 0; it < 12; it++) {
    __syncthreads();
    As[lk+0][lrow] = av.x; As[lk+1][lrow] = av.y; As[lk+2][lrow] = av.z; As[lk+3][lrow] = av.w;
    Bs[lk+0][lrow] = bv.x; Bs[lk+1][lrow] = bv.y; Bs[lk+2][lrow] = bv.z; Bs[lk+3][lrow] = bv.w;
    __syncthreads();
    if (it < 11) {
      av = *(const float4*)(Apr + (it+1)*16);
      bv = *(const float4*)(Bpr + (it+1)*16);
    }
    #pragma unroll
    for (int kk = 0; kk < 16; kk++) {
      float4 a4 = *(const float4*)&As[kk][ty*4];
      float4 b4 = *(const float4*)&Bs[kk][tx*4];
      acc[0][0] += a4.x*b4.x; acc[0][1] += a4.x*b4.y; acc[0][2] += a4.x*b4.z; acc[0][3] += a4.x*b4.w;
      acc[1][0] += a4.y*b4.x; acc[1][1] += a4.y*b4.y; acc[1][2] += a4.y*b4.z; acc[1][3] += a4.y*b4.w;
      acc[2][0] += a4.z*b4.x; acc[2][1] += a4.z*b4.y; acc[2][2] += a4.z*b4.z; acc[2][3] += a4.z*b4.w;
      acc[3][0] += a4.w*b4.x; acc[3][1] += a4.w*b4.y; acc[3][2] += a4.w*b4.z; acc[3][3] += a4.w*b4.w;
    }
  }
  float* Gb = G + (size_t)b*MAXSEG*MAXSEG;
  int col = cb + tx*4;
  #pragma unroll
  for (int i = 0; i < 4; i++) {
    float* dst = Gb + (size_t)(rb + ty*4 + i)*MAXSEG + col;
    atomicAdd(dst+0, acc[i][0]);
    atomicAdd(dst+1, acc[i][1]);
    atomicAdd(dst+2, acc[i][2]);
    atomicAdd(dst+3, acc[i][3]);
  }
}

// ---------------------------------------------------------------------------
// Kernel E1: per (b,seg) row: segment-level logsumexp + first-occurrence argmax.
// ---------------------------------------------------------------------------
__global__ __launch_bounds__(256) void k_seglse(
    const float* __restrict__ G, const int* __restrict__ allowCnt,
    const int* __restrict__ firstAllow, const int* __restrict__ nseg,
    const int* __restrict__ pos_cnt, int* __restrict__ pos_base,
    float* __restrict__ lse, int* __restrict__ amax)
{
  if (blockIdx.x == 0 && threadIdx.x == 0) {
    int acc = 0;
    pos_base[0] = 0;
    for (int b = 0; b < BB; b++) { acc += pos_cnt[b]; pos_base[b+1] = acc; }
  }
  int lane = threadIdx.x & 63, wid = threadIdx.x >> 6;
  int row = blockIdx.x * 4 + wid;
  int b = row >> 8, si = row & 255;
  if (si >= nseg[b]) return;
  const float* g = G + ((size_t)b*MAXSEG + si)*MAXSEG;
  const int* ac = allowCnt + b*MAXSEG;
  const int* fa = firstAllow + b*MAXSEG;

  float gv[4]; int av[4], fv[4];
  #pragma unroll
  for (int q = 0; q < 4; q++) {
    int s = lane + 64*q;
    gv[q] = g[s]; av[q] = ac[s]; fv[q] = fa[s];
  }
  float m = -INFINITY;
  #pragma unroll
  for (int q = 0; q < 4; q++) if (av[q] > 0) m = fmaxf(m, gv[q]);
  #pragma unroll
  for (int off = 32; off > 0; off >>= 1) m = fmaxf(m, __shfl_xor(m, off, 64));
  float s = 0.f;
  #pragma unroll
  for (int q = 0; q < 4; q++) if (av[q] > 0) s += (float)av[q] * expf(gv[q] - m);
  #pragma unroll
  for (int off = 32; off > 0; off >>= 1) s += __shfl_xor(s, off, 64);
  float bv = -INFINITY; int bi = INT_MAX;
  #pragma unroll
  for (int q = 0; q < 4; q++) {
    if (av[q] > 0 && (gv[q] > bv || (gv[q] == bv && fv[q] < bi))) { bv = gv[q]; bi = fv[q]; }
  }
  #pragma unroll
  for (int off = 32; off > 0; off >>= 1) {
    float ov = __shfl_xor(bv, off, 64);
    int   oi = __shfl_xor(bi, off, 64);
    if (ov > bv || (ov == bv && oi < bi)) { bv = ov; bi = oi; }
  }
  if (lane == 0) {
    lse[row]  = m + logf(s);
    amax[row] = bi;
  }
}

// ---------------------------------------------------------------------------
// Kernel E2: per positive row — loss + correct via precomputed lse/amax
// ---------------------------------------------------------------------------
__global__ __launch_bounds__(256) void k_pos(
    const float* __restrict__ G, const int* __restrict__ seg_id,
    const int* __restrict__ clc, const int* __restrict__ pos_local,
    const int* __restrict__ pos_base, const float* __restrict__ lse,
    const int* __restrict__ amax, float* __restrict__ accum)
{
  int r = blockIdx.x*256 + threadIdx.x;
  int lane = threadIdx.x & 63;
  int total = pos_base[BB];
  if (total > NUM_POS) total = NUM_POS;
  float l0 = 0.f, c0 = 0.f, l1 = 0.f, c1 = 0.f;
  if (r < total) {
    int b = 0;
    while (b < BB-1 && r >= pos_base[b+1]) b++;
    int k = r - pos_base[b];
    int i = pos_local[b*SS + k];
    int si = seg_id[b*SS + i];
    int L  = clc[b*SS + i];
    int sL = seg_id[b*SS + L];
    float vL = G[((size_t)b*MAXSEG + si)*MAXSEG + sL] + (clc[b*SS + L] < 0 ? 0.0f : NEG_BIG);
    float loss = lse[b*MAXSEG + si] - vL;
    float corr = (amax[b*MAXSEG + si] == L) ? 1.0f : 0.0f;
    if (r & 1) { l1 = loss; c1 = corr; } else { l0 = loss; c0 = corr; }
  }
  #pragma unroll
  for (int off = 32; off > 0; off >>= 1) {
    l0 += __shfl_down(l0, off, 64);
    c0 += __shfl_down(c0, off, 64);
    l1 += __shfl_down(l1, off, 64);
    c1 += __shfl_down(c1, off, 64);
  }
  if (lane == 0) {
    atomicAdd(&accum[0], l0);
    atomicAdd(&accum[1], c0);
    atomicAdd(&accum[2], l1);
    atomicAdd(&accum[3], c1);
  }
}

// ---------------------------------------------------------------------------
// Kernel F: finalize the 6 scalars
// ---------------------------------------------------------------------------
__global__ void k_final(const float* __restrict__ accum, float* __restrict__ out)
{
  float n = (float)(NUM_POS/2);        // 1024
  out[0] = accum[0] / n;
  out[1] = accum[1];
  out[2] = n + 1e-6f;
  out[3] = accum[2] / n;
  out[4] = accum[3];
  out[5] = n + 1e-6f;
}

// ---------------------------------------------------------------------------
extern "C" void kernel_launch(void* const* d_in, const int* in_sizes, int n_in,
                              void* d_out, int out_size, void* d_ws, size_t ws_size,
                              hipStream_t stream)
{
  const float* es   = (const float*)d_in[0];
  const float* W    = (const float*)d_in[1];
  const float* bias = (const float*)d_in[2];
  const int*   ind  = (const int*)d_in[3];
  const int*   clc  = (const int*)d_in[4];
  float* out = (float*)d_out;

  char* ws = (char*)d_ws;
  float* accum      = (float*)(ws + 0);                  // 4 floats
  int*   nseg       = (int*)(ws + 256);
  int*   pos_cnt    = (int*)(ws + 512);
  int*   pos_base   = (int*)(ws + 768);
  int*   seg_start  = (int*)(ws + 1024);                 // B*(MAXSEG+1)
  int*   seg_id     = (int*)(ws + 8192);                 // B*S
  int*   pos_local  = (int*)(ws + 40960);                // B*S
  int*   allowCnt   = (int*)(ws + 73728);                // B*256
  int*   firstAllow = (int*)(ws + 77824);
  float* lse        = (float*)(ws + 81920);
  int*   amax       = (int*)(ws + 86016);
  float* segsum     = (float*)(ws + 90112);              // B*256*768 = 3 MB
  float* Uacc       = (float*)(ws + 90112 + 3145728);    // 3 MB (accum -> tanh in-place)
  float* G          = (float*)(ws + 90112 + 2*3145728);  // 1 MB (atomic accum)

  hipMemsetAsync(accum, 0, 16, stream);
  hipMemsetAsync(Uacc, 0, 3145728, stream);
  hipMemsetAsync(G, 0, 1048576, stream);

  k_scan<<<BB, 256, 0, stream>>>(ind, clc, seg_id, seg_start, nseg, pos_local,
                                 pos_cnt, allowCnt, firstAllow);
  k_segsum<<<BB*MAXSEG, 256, 0, stream>>>(es, seg_start, nseg, segsum);
  dim3 gC(1024/64, HH/64, 3);
  k_gemmU<<<gC, 256, 0, stream>>>(segsum, W, Uacc);
  k_epiU<<<(1024*HH/4)/256, 256, 0, stream>>>(Uacc, bias);
  dim3 gD(MAXSEG/64, MAXSEG/64, BB*4);
  k_gram<<<gD, 256, 0, stream>>>(Uacc, G);
  k_seglse<<<(BB*MAXSEG)/4, 256, 0, stream>>>(G, allowCnt, firstAllow, nseg,
                                              pos_cnt, pos_base, lse, amax);
  k_pos<<<(NUM_POS+255)/256, 256, 0, stream>>>(G, seg_id, clc, pos_local,
                                               pos_base, lse, amax, accum);
  k_final<<<1, 1, 0, stream>>>(accum, out);
}

// Round 4
// 124.212 us; speedup vs baseline: 1.8005x; 1.3886x over previous
//
#include <hip/hip_runtime.h>
#include <math.h>
#include <limits.h>

#define BB 4
#define SS 2048
#define HH 768
#define MAXSEG 256
#define NUM_POS (BB*(SS/4))   // 2048
#define NEG_BIG -1000000000.0f

typedef _Float16 f16x8 __attribute__((ext_vector_type(8)));
typedef _Float16 f16x4 __attribute__((ext_vector_type(4)));
typedef float    f32x4 __attribute__((ext_vector_type(4)));

// ---------------------------------------------------------------------------
// Kernel A: per-batch scans (one block per batch, shfl-based)
// ---------------------------------------------------------------------------
__global__ __launch_bounds__(256) void k_scan(
    const int* __restrict__ ind, const int* __restrict__ clc,
    int* __restrict__ seg_id, int* __restrict__ seg_start,
    int* __restrict__ nseg, int* __restrict__ pos_local, int* __restrict__ pos_cnt,
    int* __restrict__ allowCnt, int* __restrict__ firstAllow)
{
  int b = blockIdx.x, t = threadIdx.x;
  int lane = t & 63, wid = t >> 6;
  __shared__ int sInd[SS];
  __shared__ int sWave[4];
  __shared__ int sAC[MAXSEG];
  __shared__ int sFA[MAXSEG];
  for (int i = t; i < SS; i += 256) sInd[i] = ind[b*SS + i];
  sAC[t] = 0; sFA[t] = INT_MAX;
  __syncthreads();

  int i0 = t * 8;
  int f[8], cv[8];
  int lsum = 0;
  #pragma unroll
  for (int u = 0; u < 8; u++) {
    int i = i0 + u;
    f[u] = (i == 0) ? 0 : (sInd[i] != sInd[i-1]);
    cv[u] = clc[b*SS + i];
    lsum += f[u];
  }
  int x = lsum;
  #pragma unroll
  for (int off = 1; off < 64; off <<= 1) {
    int v = __shfl_up(x, off, 64);
    if (lane >= off) x += v;
  }
  if (lane == 63) sWave[wid] = x;
  __syncthreads();
  int base = 0;
  for (int w = 0; w < wid; w++) base += sWave[w];
  int run = base + x - lsum;
  int rid[8];
  #pragma unroll
  for (int u = 0; u < 8; u++) {
    int i = i0 + u;
    run += f[u];
    rid[u] = run;
    seg_id[b*SS + i] = run;
    if (f[u] || i == 0) seg_start[b*(MAXSEG+1) + run] = i;
  }
  if (t == 255) { nseg[b] = run + 1; seg_start[b*(MAXSEG+1) + run + 1] = SS; }

  #pragma unroll
  for (int u = 0; u < 8; u++) {
    if (cv[u] < 0) {
      atomicAdd(&sAC[rid[u]], 1);
      atomicMin(&sFA[rid[u]], i0 + u);
    }
  }
  __syncthreads();
  allowCnt[b*MAXSEG + t]   = sAC[t];
  firstAllow[b*MAXSEG + t] = sFA[t];

  int psum = 0;
  int p[8];
  #pragma unroll
  for (int u = 0; u < 8; u++) { p[u] = (cv[u] > 0) ? 1 : 0; psum += p[u]; }
  x = psum;
  #pragma unroll
  for (int off = 1; off < 64; off <<= 1) {
    int v = __shfl_up(x, off, 64);
    if (lane >= off) x += v;
  }
  __syncthreads();
  if (lane == 63) sWave[wid] = x;
  __syncthreads();
  base = 0;
  for (int w = 0; w < wid; w++) base += sWave[w];
  int rank = base + x - psum;
  #pragma unroll
  for (int u = 0; u < 8; u++) {
    if (p[u]) { pos_local[b*SS + rank] = i0 + u; rank++; }
  }
  if (t == 255) pos_cnt[b] = rank;
}

// ---------------------------------------------------------------------------
// Kernel B: segment sums (f32 accumulate -> f16 out) + fused W f32->f16 cast.
// Blocks [0, BB*MAXSEG): segment sums. Blocks [BB*MAXSEG, +576): W cast.
// ---------------------------------------------------------------------------
__global__ __launch_bounds__(256) void k_segsum(
    const float* __restrict__ es, const float* __restrict__ W,
    const int* __restrict__ seg_start, const int* __restrict__ nseg,
    _Float16* __restrict__ segsum_h, _Float16* __restrict__ Wh)
{
  int blk = blockIdx.x, t = threadIdx.x;
  if (blk >= BB*MAXSEG) {
    int idx = (blk - BB*MAXSEG)*256 + t;     // float4 index; 147456 total
    float4 v = ((const float4*)W)[idx];
    f16x4 h;
    h[0] = (_Float16)v.x; h[1] = (_Float16)v.y;
    h[2] = (_Float16)v.z; h[3] = (_Float16)v.w;
    *(f16x4*)(Wh + (size_t)idx*4) = h;
    return;
  }
  int b = blk >> 8, s = blk & 255;
  _Float16* o = segsum_h + ((size_t)b*MAXSEG + s)*HH;
  if (s >= nseg[b]) {   // zero-fill missing segments (keep downstream NaN-free)
    o[t] = (_Float16)0.f; o[t+256] = (_Float16)0.f; o[t+512] = (_Float16)0.f;
    return;
  }
  int st = seg_start[b*(MAXSEG+1) + s];
  int en = seg_start[b*(MAXSEG+1) + s + 1];
  const float* base = es + (size_t)b*SS*HH;
  float a0 = 0.f, a1 = 0.f, a2 = 0.f;
  for (int i = st; i < en; i++) {
    const float* r = base + (size_t)i*HH;
    a0 += r[t]; a1 += r[t+256]; a2 += r[t+512];
  }
  o[t] = (_Float16)a0; o[t+256] = (_Float16)a1; o[t+512] = (_Float16)a2;
}

// ---------------------------------------------------------------------------
// Kernel C: U = tanh(segsum @ W^T + bias), f16 MFMA, direct-global fragments.
// Wave = independent 32x32 tile (2x2 of 16x16x32). 768 tiles -> 192 blocks.
// A/B fragment: lane holds row (tile+lane&15), 8 contiguous k at quad*8.
// C/D layout: col = lane&15, row = quad*4 + reg.
// ---------------------------------------------------------------------------
__global__ __launch_bounds__(256) void k_gemmU(
    const _Float16* __restrict__ Ah, const _Float16* __restrict__ Wh,
    const float* __restrict__ bias, _Float16* __restrict__ Uh)
{
  int tid = threadIdx.x;
  int w = tid >> 6, lane = tid & 63;
  int tile = blockIdx.x*4 + w;          // 0..767 over 32 x 24 tiles
  int tm = tile / 24, tn = tile % 24;
  int rb = tm*32, cb = tn*32;
  int m0 = lane & 15, quad = lane >> 4;
  const _Float16* A0 = Ah + (size_t)(rb + m0)*HH + quad*8;
  const _Float16* A1 = A0 + (size_t)16*HH;
  const _Float16* B0 = Wh + (size_t)(cb + m0)*HH + quad*8;
  const _Float16* B1 = B0 + (size_t)16*HH;
  f32x4 acc00 = {0.f,0.f,0.f,0.f}, acc01 = {0.f,0.f,0.f,0.f};
  f32x4 acc10 = {0.f,0.f,0.f,0.f}, acc11 = {0.f,0.f,0.f,0.f};
  #pragma unroll 4
  for (int k0 = 0; k0 < HH; k0 += 32) {
    f16x8 a0 = *(const f16x8*)(A0 + k0);
    f16x8 a1 = *(const f16x8*)(A1 + k0);
    f16x8 b0 = *(const f16x8*)(B0 + k0);
    f16x8 b1 = *(const f16x8*)(B1 + k0);
    acc00 = __builtin_amdgcn_mfma_f32_16x16x32_f16(a0, b0, acc00, 0, 0, 0);
    acc01 = __builtin_amdgcn_mfma_f32_16x16x32_f16(a0, b1, acc01, 0, 0, 0);
    acc10 = __builtin_amdgcn_mfma_f32_16x16x32_f16(a1, b0, acc10, 0, 0, 0);
    acc11 = __builtin_amdgcn_mfma_f32_16x16x32_f16(a1, b1, acc11, 0, 0, 0);
  }
  float bc0 = bias[cb + m0], bc1 = bias[cb + 16 + m0];
  int r0 = rb + quad*4;
  #pragma unroll
  for (int i = 0; i < 4; i++) {
    Uh[(size_t)(r0+i)*HH    + cb + m0]      = (_Float16)tanhf(acc00[i] + bc0);
    Uh[(size_t)(r0+i)*HH    + cb + 16 + m0] = (_Float16)tanhf(acc01[i] + bc1);
    Uh[(size_t)(r0+16+i)*HH + cb + m0]      = (_Float16)tanhf(acc10[i] + bc0);
    Uh[(size_t)(r0+16+i)*HH + cb + 16 + m0] = (_Float16)tanhf(acc11[i] + bc1);
  }
}

// ---------------------------------------------------------------------------
// Kernel D: Gram G[b] = U[b] U[b]^T, f16 MFMA. Wave = one 16x16 tile.
// 4 batches x 16 x 16 tiles = 1024 waves -> 256 blocks.
// ---------------------------------------------------------------------------
__global__ __launch_bounds__(256) void k_gram(
    const _Float16* __restrict__ Uh, float* __restrict__ G)
{
  int tid = threadIdx.x;
  int w = tid >> 6, lane = tid & 63;
  int tile = blockIdx.x*4 + w;          // 0..1023
  int b = tile >> 8, rem = tile & 255;
  int rb = (rem >> 4)*16, cb = (rem & 15)*16;
  int m0 = lane & 15, quad = lane >> 4;
  const _Float16* Ub = Uh + (size_t)b*MAXSEG*HH;
  const _Float16* A0 = Ub + (size_t)(rb + m0)*HH + quad*8;
  const _Float16* B0 = Ub + (size_t)(cb + m0)*HH + quad*8;
  f32x4 acc = {0.f,0.f,0.f,0.f};
  #pragma unroll 4
  for (int k0 = 0; k0 < HH; k0 += 32) {
    f16x8 a  = *(const f16x8*)(A0 + k0);
    f16x8 bb = *(const f16x8*)(B0 + k0);
    acc = __builtin_amdgcn_mfma_f32_16x16x32_f16(a, bb, acc, 0, 0, 0);
  }
  float* Gb = G + (size_t)b*MAXSEG*MAXSEG;
  int r0 = rb + quad*4;
  #pragma unroll
  for (int i = 0; i < 4; i++)
    Gb[(size_t)(r0+i)*MAXSEG + cb + m0] = acc[i];
}

// ---------------------------------------------------------------------------
// Kernel E1: per (b,seg) row: segment-level logsumexp + first-occurrence argmax
// ---------------------------------------------------------------------------
__global__ __launch_bounds__(256) void k_seglse(
    const float* __restrict__ G, const int* __restrict__ allowCnt,
    const int* __restrict__ firstAllow, const int* __restrict__ nseg,
    float* __restrict__ lse, int* __restrict__ amax)
{
  int lane = threadIdx.x & 63, wid = threadIdx.x >> 6;
  int row = blockIdx.x * 4 + wid;
  int b = row >> 8, si = row & 255;
  if (si >= nseg[b]) return;
  const float* g = G + ((size_t)b*MAXSEG + si)*MAXSEG;
  const int* ac = allowCnt + b*MAXSEG;
  const int* fa = firstAllow + b*MAXSEG;

  float gv[4]; int av[4], fv[4];
  #pragma unroll
  for (int q = 0; q < 4; q++) {
    int s = lane + 64*q;
    gv[q] = g[s]; av[q] = ac[s]; fv[q] = fa[s];
  }
  float m = -INFINITY;
  #pragma unroll
  for (int q = 0; q < 4; q++) if (av[q] > 0) m = fmaxf(m, gv[q]);
  #pragma unroll
  for (int off = 32; off > 0; off >>= 1) m = fmaxf(m, __shfl_xor(m, off, 64));
  float s = 0.f;
  #pragma unroll
  for (int q = 0; q < 4; q++) if (av[q] > 0) s += (float)av[q] * expf(gv[q] - m);
  #pragma unroll
  for (int off = 32; off > 0; off >>= 1) s += __shfl_xor(s, off, 64);
  float bv = -INFINITY; int bi = INT_MAX;
  #pragma unroll
  for (int q = 0; q < 4; q++) {
    if (av[q] > 0 && (gv[q] > bv || (gv[q] == bv && fv[q] < bi))) { bv = gv[q]; bi = fv[q]; }
  }
  #pragma unroll
  for (int off = 32; off > 0; off >>= 1) {
    float ov = __shfl_xor(bv, off, 64);
    int   oi = __shfl_xor(bi, off, 64);
    if (ov > bv || (ov == bv && oi < bi)) { bv = ov; bi = oi; }
  }
  if (lane == 0) {
    lse[row]  = m + logf(s);
    amax[row] = bi;
  }
}

// ---------------------------------------------------------------------------
// Kernel E2: single block — all positives, LDS reduction, finalize 6 scalars.
// ---------------------------------------------------------------------------
__global__ __launch_bounds__(256) void k_posfinal(
    const float* __restrict__ G, const int* __restrict__ seg_id,
    const int* __restrict__ clc, const int* __restrict__ pos_local,
    const int* __restrict__ pos_cnt, const float* __restrict__ lse,
    const int* __restrict__ amax, float* __restrict__ out)
{
  __shared__ int sBase[BB+1];
  __shared__ float sL0[4], sC0[4], sL1[4], sC1[4];
  int t = threadIdx.x;
  if (t == 0) {
    int acc = 0; sBase[0] = 0;
    for (int b = 0; b < BB; b++) { acc += pos_cnt[b]; sBase[b+1] = acc; }
  }
  __syncthreads();
  int total = sBase[BB];
  if (total > NUM_POS) total = NUM_POS;
  float l0 = 0.f, c0 = 0.f, l1 = 0.f, c1 = 0.f;
  for (int r = t; r < total; r += 256) {
    int b = 0;
    while (b < BB-1 && r >= sBase[b+1]) b++;
    int k = r - sBase[b];
    int i  = pos_local[b*SS + k];
    int si = seg_id[b*SS + i];
    int L  = clc[b*SS + i];
    int sL = seg_id[b*SS + L];
    float vL = G[((size_t)b*MAXSEG + si)*MAXSEG + sL] + (clc[b*SS + L] < 0 ? 0.0f : NEG_BIG);
    float loss = lse[b*MAXSEG + si] - vL;
    float corr = (amax[b*MAXSEG + si] == L) ? 1.0f : 0.0f;
    if (r & 1) { l1 += loss; c1 += corr; } else { l0 += loss; c0 += corr; }
  }
  int lane = t & 63, wid = t >> 6;
  #pragma unroll
  for (int off = 32; off > 0; off >>= 1) {
    l0 += __shfl_down(l0, off, 64);
    c0 += __shfl_down(c0, off, 64);
    l1 += __shfl_down(l1, off, 64);
    c1 += __shfl_down(c1, off, 64);
  }
  if (lane == 0) { sL0[wid] = l0; sC0[wid] = c0; sL1[wid] = l1; sC1[wid] = c1; }
  __syncthreads();
  if (t == 0) {
    float L0 = sL0[0]+sL0[1]+sL0[2]+sL0[3];
    float C0 = sC0[0]+sC0[1]+sC0[2]+sC0[3];
    float L1 = sL1[0]+sL1[1]+sL1[2]+sL1[3];
    float C1 = sC1[0]+sC1[1]+sC1[2]+sC1[3];
    float n = (float)(NUM_POS/2);   // 1024
    out[0] = L0 / n;
    out[1] = C0;
    out[2] = n + 1e-6f;
    out[3] = L1 / n;
    out[4] = C1;
    out[5] = n + 1e-6f;
  }
}

// ---------------------------------------------------------------------------
extern "C" void kernel_launch(void* const* d_in, const int* in_sizes, int n_in,
                              void* d_out, int out_size, void* d_ws, size_t ws_size,
                              hipStream_t stream)
{
  const float* es   = (const float*)d_in[0];
  const float* W    = (const float*)d_in[1];
  const float* bias = (const float*)d_in[2];
  const int*   ind  = (const int*)d_in[3];
  const int*   clc  = (const int*)d_in[4];
  float* out = (float*)d_out;

  char* ws = (char*)d_ws;
  int*   nseg       = (int*)(ws + 0);
  int*   pos_cnt    = (int*)(ws + 256);
  int*   seg_start  = (int*)(ws + 1024);                 // B*(MAXSEG+1)
  int*   seg_id     = (int*)(ws + 8192);                 // B*S
  int*   pos_local  = (int*)(ws + 40960);                // B*S
  int*   allowCnt   = (int*)(ws + 73728);                // B*256
  int*   firstAllow = (int*)(ws + 77824);
  float* lse        = (float*)(ws + 81920);
  int*   amax       = (int*)(ws + 86016);
  _Float16* segsum_h = (_Float16*)(ws + 90112);          // 1024*768*2 = 1.5 MB
  _Float16* Wh       = (_Float16*)(ws + 1662976);        // 768*768*2 = 1.125 MB
  _Float16* Uh       = (_Float16*)(ws + 2842624);        // 1.5 MB
  float*    G        = (float*)(ws + 4415488);           // 1 MB

  k_scan<<<BB, 256, 0, stream>>>(ind, clc, seg_id, seg_start, nseg, pos_local,
                                 pos_cnt, allowCnt, firstAllow);
  k_segsum<<<BB*MAXSEG + 576, 256, 0, stream>>>(es, W, seg_start, nseg, segsum_h, Wh);
  k_gemmU<<<192, 256, 0, stream>>>(segsum_h, Wh, bias, Uh);
  k_gram<<<256, 256, 0, stream>>>(Uh, G);
  k_seglse<<<(BB*MAXSEG)/4, 256, 0, stream>>>(G, allowCnt, firstAllow, nseg, lse, amax);
  k_posfinal<<<1, 256, 0, stream>>>(G, seg_id, clc, pos_local, pos_cnt, lse, amax, out);
}